// Round 5
// baseline (63.806 us; speedup 1.0000x reference)
//
#include <hip/hip_runtime.h>
#include <math.h>

// One WAVE per walker, block = 128 = 2 independent walkers, ZERO LDS / barriers.
// lane = s*32 + hl: half-wave per spin. h global->reg once (reused for store);
// dot via register W + 32-lane halving butterfly (lane hl ends with M-entry hl);
// M handed to det lanes via __shfl gathers; serial pivoted 7x7 dets on 16 lanes;
// anti broadcast via __shfl; store from register-held h.

__global__ __launch_bounds__(128, 3)
void orbital_cof_kernel(const float* __restrict__ h_g,   // (B,16,256)
                        const float* __restrict__ r_g,   // (B,16,4,3)
                        const float* __restrict__ W_g,   // (2,256,8)
                        const float* __restrict__ b_g,   // (2,8)
                        const float* __restrict__ dec_g, // (2,4,8)
                        const float* __restrict__ pi_g,  // (2,4,8)
                        float* __restrict__ out,         // (2,B,8,256)
                        int nb)
{
    const int t = threadIdx.x;
    const int wave = t >> 6;
    const int lane = t & 63;
    const int b = blockIdx.x * 2 + wave;
    if (b >= nb) return;                 // no barriers anywhere: safe

    const int s  = lane >> 5;            // spin
    const int hl = lane & 31;            // lane within spin half

    // ---- distance held by this lane: (s,n,i) = (lane>>5,(lane>>2)&7,lane&3) ----
    float dist;
    {
        const float* rp = r_g + (size_t)b * 192 + lane * 3;
        float x = rp[0], y = rp[1], z = rp[2];
        dist = sqrtf(x * x + y * y + z * z);
    }

    // ---- h: spin-s rows, d in [hl*8, hl*8+8); 16 coalesced float4, read ONCE ----
    float4 hv[8][2];
    {
        const float* hb = h_g + (size_t)b * 4096 + s * 2048 + hl * 8;
#pragma unroll
        for (int n = 0; n < 8; ++n) {
            hv[n][0] = *(const float4*)(hb + n * 256);
            hv[n][1] = *(const float4*)(hb + n * 256 + 4);
        }
    }

    // ---- dot + butterfly per k-half; lane hl ends holding M[s][hl>>2][kh*4+(hl&3)] ----
    float mA = 0.f, mB = 0.f;
#pragma unroll
    for (int kh = 0; kh < 2; ++kh) {
        float wv[8][4];                  // W[s][hl*8+dd][kh*4+kk], L1/L2-hot
        const float* wp = W_g + s * 2048 + hl * 64 + kh * 4;
#pragma unroll
        for (int dd = 0; dd < 8; ++dd) {
            float4 w = *(const float4*)(wp + dd * 8);
            wv[dd][0] = w.x; wv[dd][1] = w.y; wv[dd][2] = w.z; wv[dd][3] = w.w;
        }
        float v[32];
#pragma unroll
        for (int n = 0; n < 8; ++n) {
            float h0 = hv[n][0].x, h1 = hv[n][0].y, h2 = hv[n][0].z, h3 = hv[n][0].w;
            float h4 = hv[n][1].x, h5 = hv[n][1].y, h6 = hv[n][1].z, h7 = hv[n][1].w;
#pragma unroll
            for (int kk = 0; kk < 4; ++kk) {
                float acc = h0 * wv[0][kk];
                acc = fmaf(h1, wv[1][kk], acc);
                acc = fmaf(h2, wv[2][kk], acc);
                acc = fmaf(h3, wv[3][kk], acc);
                acc = fmaf(h4, wv[4][kk], acc);
                acc = fmaf(h5, wv[5][kk], acc);
                acc = fmaf(h6, wv[6][kk], acc);
                acc = fmaf(h7, wv[7][kk], acc);
                v[n * 4 + kk] = acc;
            }
        }
        // halving butterfly within the 32-lane half (xor masks stay in-half).
        // Stage with mask m keeps half selected by bit(m): lane hl -> index hl.
#pragma unroll
        for (int i = 0; i < 16; ++i) {
            float send = (hl & 16) ? v[i] : v[i + 16];
            float recv = __shfl_xor(send, 16);
            v[i] = ((hl & 16) ? v[i + 16] : v[i]) + recv;
        }
#pragma unroll
        for (int i = 0; i < 8; ++i) {
            float send = (hl & 8) ? v[i] : v[i + 8];
            float recv = __shfl_xor(send, 8);
            v[i] = ((hl & 8) ? v[i + 8] : v[i]) + recv;
        }
#pragma unroll
        for (int i = 0; i < 4; ++i) {
            float send = (hl & 4) ? v[i] : v[i + 4];
            float recv = __shfl_xor(send, 4);
            v[i] = ((hl & 4) ? v[i + 4] : v[i]) + recv;
        }
#pragma unroll
        for (int i = 0; i < 2; ++i) {
            float send = (hl & 2) ? v[i] : v[i + 2];
            float recv = __shfl_xor(send, 2);
            v[i] = ((hl & 2) ? v[i + 2] : v[i]) + recv;
        }
        {
            float send = (hl & 1) ? v[0] : v[1];
            float recv = __shfl_xor(send, 1);
            v[0] = ((hl & 1) ? v[1] : v[0]) + recv;
        }
        if (kh == 0) mA = v[0]; else mB = v[0];
    }

    // ---- env + bias applied to this lane's two M entries ----
    {
        const int nm = hl >> 2;          // my n
        const int kl = hl & 3;
        float dn[4];
#pragma unroll
        for (int i = 0; i < 4; ++i)
            dn[i] = __shfl(dist, s * 32 + nm * 4 + i);
        const int kA = kl, kB = kl + 4;
        float envA = 0.f, envB = 0.f;
#pragma unroll
        for (int i = 0; i < 4; ++i) {
            envA = fmaf(pi_g[s * 32 + i * 8 + kA], __expf(-dn[i] * dec_g[s * 32 + i * 8 + kA]), envA);
            envB = fmaf(pi_g[s * 32 + i * 8 + kB], __expf(-dn[i] * dec_g[s * 32 + i * 8 + kB]), envB);
        }
        mA = (mA + b_g[s * 8 + kA]) * envA;
        mB = (mB + b_g[s * 8 + kB]) * envB;
    }

    // ---- gather the 7x7 minor for det-lane nd = hl&7 (M[s][n][k] lives at
    //      lane s*32 + n*4 + (k&3): mA for k<4, mB for k>=4) ----
    const int nd = hl & 7;
    const int base = s * 32;
    float a[7][7];
#pragma unroll
    for (int i = 0; i < 7; ++i) {
        int src = i + (i >= nd ? 1 : 0);         // skip row nd
#pragma unroll
        for (int j = 0; j < 7; ++j) {
            const int k = j + 1;                 // skip col 0
            int sl = base + src * 4 + (k & 3);
            a[i][j] = (k < 4) ? __shfl(mA, sl) : __shfl(mB, sl);
        }
    }
    float m0 = __shfl(mA, base + nd * 4);        // M[s][nd][0]

    // ---- 16 serial pivoted 7x7 dets (lanes hl<8 of each half) ----
    float anti = 0.f;
    if (hl < 8) {
        float det = 1.f;
#pragma unroll
        for (int kk = 0; kk < 7; ++kk) {
#pragma unroll
            for (int i = kk + 1; i < 7; ++i) {
                bool sw = fabsf(a[i][kk]) > fabsf(a[kk][kk]);
#pragma unroll
                for (int j = kk; j < 7; ++j) {
                    float tk = a[kk][j], ti = a[i][j];
                    a[kk][j] = sw ? ti : tk;
                    a[i][j]  = sw ? tk : ti;
                }
                det = sw ? -det : det;
            }
            float piv = a[kk][kk];
            det *= piv;
            float rp = (piv != 0.f) ? (1.f / piv) : 0.f;
#pragma unroll
            for (int i = kk + 1; i < 7; ++i) {
                float f = a[i][kk] * rp;
#pragma unroll
                for (int j = kk + 1; j < 7; ++j) a[i][j] = fmaf(-f, a[kk][j], a[i][j]);
            }
        }
        anti = m0 * ((nd & 1) ? -1.f : 1.f) * det;
    }

    // ---- store out = h * anti from register-held h (anti via shuffle) ----
    float* ob = out + (size_t)s * (size_t)nb * 2048 + (size_t)b * 2048 + hl * 8;
#pragma unroll
    for (int n = 0; n < 8; ++n) {
        float an = __shfl(anti, s * 32 + n);
        float4 o0 = make_float4(hv[n][0].x * an, hv[n][0].y * an,
                                hv[n][0].z * an, hv[n][0].w * an);
        float4 o1 = make_float4(hv[n][1].x * an, hv[n][1].y * an,
                                hv[n][1].z * an, hv[n][1].w * an);
        *(float4*)(ob + n * 256)     = o0;
        *(float4*)(ob + n * 256 + 4) = o1;
    }
}

extern "C" void kernel_launch(void* const* d_in, const int* in_sizes, int n_in,
                              void* d_out, int out_size, void* d_ws, size_t ws_size,
                              hipStream_t stream) {
    int nb = in_sizes[0] / 4096;      // B = elems / (S*N*D)
    const float* h_g   = (const float*)d_in[0];
    const float* r_g   = (const float*)d_in[1];
    const float* W_g   = (const float*)d_in[2];
    const float* b_g   = (const float*)d_in[3];
    const float* dec_g = (const float*)d_in[4];
    const float* pi_g  = (const float*)d_in[5];
    int grid = (nb + 1) / 2;
    orbital_cof_kernel<<<dim3(grid), dim3(128), 0, stream>>>(
        h_g, r_g, W_g, b_g, dec_g, pi_g, (float*)d_out, nb);
}